// Round 2
// baseline (1936.303 us; speedup 1.0000x reference)
//
#include <hip/hip_runtime.h>
#include <hip/hip_fp16.h>

#define N_NODES 50000
#define DIM 256
#define HID 128
#define LAT 64
#define NV 3
#define NE 1600000
#define NP 10000

// ---------- bf16 helpers (raw ushort/uint, RNE) ----------
__device__ __forceinline__ unsigned f2bf1(float f) {
  unsigned x = __float_as_uint(f);
  return (x + 0x7fffu + ((x >> 16) & 1u)) >> 16;
}
__device__ __forceinline__ unsigned pack2bf(float a, float b) {
  return (f2bf1(a) & 0xffffu) | (f2bf1(b) << 16);
}
__device__ __forceinline__ float bf2f(unsigned short u) {
  return __uint_as_float(((unsigned)u) << 16);
}

// ---------- K1: XW[v] = X @ W[v]  (f32 in, bf16 out) ----------
__global__ __launch_bounds__(256) void k_gemm_xw(const float* __restrict__ X,
                                                 const float* __restrict__ W,
                                                 unsigned* __restrict__ XWu) {
  const int v = blockIdx.y;
  const int nbase = blockIdx.x * 64;
  __shared__ float Xs[64][65];
  __shared__ float Ws[64][128];
  const int tid = threadIdx.x;
  const int hgrp = tid & 15, ngrp = tid >> 4;
  const int h0 = hgrp * 8, n0 = ngrp * 4;
  float acc[4][8];
#pragma unroll
  for (int i = 0; i < 4; i++)
#pragma unroll
    for (int j = 0; j < 8; j++) acc[i][j] = 0.f;
  const float* Wv = W + (size_t)v * DIM * HID;
  for (int kc = 0; kc < DIM; kc += 64) {
#pragma unroll
    for (int i = 0; i < 16; i++) {
      int idx = i * 256 + tid;
      int r = idx >> 6, c = idx & 63;
      int n = nbase + r;
      Xs[r][c] = (n < N_NODES) ? X[(size_t)n * DIM + kc + c] : 0.f;
    }
#pragma unroll
    for (int i = 0; i < 32; i++) {
      int idx = i * 256 + tid;
      int r = idx >> 7, c = idx & 127;
      Ws[r][c] = Wv[(size_t)(kc + r) * HID + c];
    }
    __syncthreads();
#pragma unroll 8
    for (int k = 0; k < 64; k++) {
      float4 w0 = *reinterpret_cast<const float4*>(&Ws[k][h0]);
      float4 w1 = *reinterpret_cast<const float4*>(&Ws[k][h0 + 4]);
      float xs[4];
#pragma unroll
      for (int i = 0; i < 4; i++) xs[i] = Xs[n0 + i][k];
#pragma unroll
      for (int i = 0; i < 4; i++) {
        acc[i][0] += xs[i] * w0.x; acc[i][1] += xs[i] * w0.y;
        acc[i][2] += xs[i] * w0.z; acc[i][3] += xs[i] * w0.w;
        acc[i][4] += xs[i] * w1.x; acc[i][5] += xs[i] * w1.y;
        acc[i][6] += xs[i] * w1.z; acc[i][7] += xs[i] * w1.w;
      }
    }
    __syncthreads();
  }
#pragma unroll
  for (int i = 0; i < 4; i++) {
    int n = nbase + n0 + i;
    if (n >= N_NODES) break;
    uint4 u;
    u.x = pack2bf(acc[i][0], acc[i][1]);
    u.y = pack2bf(acc[i][2], acc[i][3]);
    u.z = pack2bf(acc[i][4], acc[i][5]);
    u.w = pack2bf(acc[i][6], acc[i][7]);
    *reinterpret_cast<uint4*>(XWu + (((size_t)v * N_NODES + n) * HID + h0) / 2) = u;
  }
}

// ---------- K2: histogram of dst per view ----------
__global__ void k_count(const int* __restrict__ edge_idx, int* __restrict__ counts) {
  const int v = blockIdx.y;
  const int stride = gridDim.x * blockDim.x;
  for (int e = blockIdx.x * blockDim.x + threadIdx.x; e < NE; e += stride) {
    int dst = edge_idx[((size_t)v * NE + e) * 2 + 1];
    atomicAdd(&counts[v * N_NODES + dst], 1);
  }
}

// ---------- K3: exclusive scan per view (shfl-based, 2 barriers/chunk) ----------
__global__ __launch_bounds__(1024) void k_scan(const int* __restrict__ counts,
                                               int* __restrict__ offsets,
                                               int* __restrict__ cursor) {
  const int v = blockIdx.x;
  __shared__ int wsum[16];
  __shared__ int carry_s;
  const int tid = threadIdx.x;
  const int lane = tid & 63, wv = tid >> 6;
  if (tid == 0) carry_s = 0;
  __syncthreads();
  for (int base = 0; base < N_NODES; base += 1024) {
    int i = base + tid;
    int val = (i < N_NODES) ? counts[v * N_NODES + i] : 0;
    int x = val;  // inclusive wave scan
#pragma unroll
    for (int off = 1; off < 64; off <<= 1) {
      int t = __shfl_up(x, off);
      if (lane >= off) x += t;
    }
    if (lane == 63) wsum[wv] = x;
    __syncthreads();
    int wpre = 0;
#pragma unroll
    for (int w = 0; w < 15; w++) wpre += (w < wv) ? wsum[w] : 0;
    int excl = carry_s + wpre + x - val;
    if (i < N_NODES) {
      offsets[v * N_NODES + i] = excl;
      cursor[v * N_NODES + i] = excl;
    }
    __syncthreads();
    if (tid == 1023) carry_s += wpre + x;  // chunk total = prefix of last wave + its inclusive
    __syncthreads();
  }
}

// ---------- K4: rank-scatter edges; payload packed to 4B (src:16 | f16 val:16) ----------
__global__ void k_scatter(const int* __restrict__ edge_idx,
                          const float* __restrict__ edge_vals,
                          int* __restrict__ cursor,
                          unsigned* __restrict__ spack) {
  const int v = blockIdx.y;
  const int stride = gridDim.x * blockDim.x;
  for (int e = blockIdx.x * blockDim.x + threadIdx.x; e < NE; e += stride) {
    size_t eb = (size_t)v * NE + e;
    int2 sd = reinterpret_cast<const int2*>(edge_idx)[eb];  // (src, dst)
    float val = edge_vals[eb];
    int pos = atomicAdd(&cursor[v * N_NODES + sd.y], 1);
    unsigned h = (unsigned)__half_as_ushort(__float2half(val));
    spack[(size_t)v * NE + pos] = (((unsigned)sd.x) << 16) | h;
  }
}

// ---------- K5: CSR aggregate + bias + relu -> concat (bf16) ----------
__global__ __launch_bounds__(256) void k_agg(const int* __restrict__ counts,
                                             const int* __restrict__ offsets,
                                             const unsigned* __restrict__ spack,
                                             const unsigned* __restrict__ XWu,
                                             const float* __restrict__ b,
                                             unsigned* __restrict__ cat) {
  const int v = blockIdx.y;
  const int wave = threadIdx.x >> 6;
  const int lane = threadIdx.x & 63;
  const int n = blockIdx.x * 4 + wave;
  if (n >= N_NODES) return;
  const int cnt = counts[v * N_NODES + n];
  const int base = offsets[v * N_NODES + n];
  const unsigned* xw = XWu + (size_t)v * N_NODES * 64;  // 64 uints (=128 bf16) per row
  const unsigned* pp = spack + (size_t)v * NE + base;
  float a0 = 0.f, a1 = 0.f;
  int c0 = 0;
  for (; c0 + 64 <= cnt; c0 += 64) {
    unsigned p = pp[c0 + lane];
#pragma unroll
    for (int j = 0; j < 64; j++) {
      unsigned pj = __shfl((int)p, j);
      float val = __half2float(__ushort_as_half((unsigned short)(pj & 0xffffu)));
      unsigned u = xw[(size_t)(pj >> 16) * 64 + lane];
      a0 += val * __uint_as_float(u << 16);
      a1 += val * __uint_as_float(u & 0xffff0000u);
    }
  }
  const int rem = cnt - c0;
  if (rem > 0) {
    unsigned p = (lane < rem) ? pp[c0 + lane] : 0u;
    for (int j = 0; j < rem; j++) {
      unsigned pj = __shfl((int)p, j);
      float val = __half2float(__ushort_as_half((unsigned short)(pj & 0xffffu)));
      unsigned u = xw[(size_t)(pj >> 16) * 64 + lane];
      a0 += val * __uint_as_float(u << 16);
      a1 += val * __uint_as_float(u & 0xffff0000u);
    }
  }
  float h0 = a0 + b[v * HID + 2 * lane];
  float h1 = a1 + b[v * HID + 2 * lane + 1];
  h0 = h0 > 0.f ? h0 : 0.f;
  h1 = h1 > 0.f ? h1 : 0.f;
  cat[(size_t)n * 192 + v * 64 + lane] = pack2bf(h0, h1);
}

// ---------- K6: mu/sigma = concat @ [Wmu|Wsig] + bias, elu ----------
__global__ __launch_bounds__(256) void k_musig(const unsigned short* __restrict__ catus,
                                               const float* __restrict__ Wmu,
                                               const float* __restrict__ bmu,
                                               const float* __restrict__ Wsig,
                                               const float* __restrict__ bsig,
                                               float* __restrict__ mu,
                                               float* __restrict__ sig) {
  const int nbase = blockIdx.x * 64;
  __shared__ float Cs[64][65];
  __shared__ float Ws[64][128];
  const int tid = threadIdx.x;
  const int ogrp = tid & 15, ngrp = tid >> 4;
  const int o0 = ogrp * 8, n0 = ngrp * 4;
  float acc[4][8];
#pragma unroll
  for (int i = 0; i < 4; i++)
#pragma unroll
    for (int j = 0; j < 8; j++) acc[i][j] = 0.f;
  for (int kc = 0; kc < 384; kc += 64) {
#pragma unroll
    for (int i = 0; i < 16; i++) {
      int idx = i * 256 + tid;
      int r = idx >> 6, c = idx & 63;
      int n = nbase + r;
      Cs[r][c] = (n < N_NODES) ? bf2f(catus[(size_t)n * 384 + kc + c]) : 0.f;
    }
#pragma unroll
    for (int i = 0; i < 32; i++) {
      int idx = i * 256 + tid;
      int r = idx >> 7, c = idx & 127;
      int k = kc + r;
      Ws[r][c] = (c < 64) ? Wmu[(size_t)k * 64 + c] : Wsig[(size_t)k * 64 + (c - 64)];
    }
    __syncthreads();
#pragma unroll 8
    for (int k = 0; k < 64; k++) {
      float4 w0 = *reinterpret_cast<const float4*>(&Ws[k][o0]);
      float4 w1 = *reinterpret_cast<const float4*>(&Ws[k][o0 + 4]);
      float xs[4];
#pragma unroll
      for (int i = 0; i < 4; i++) xs[i] = Cs[n0 + i][k];
#pragma unroll
      for (int i = 0; i < 4; i++) {
        acc[i][0] += xs[i] * w0.x; acc[i][1] += xs[i] * w0.y;
        acc[i][2] += xs[i] * w0.z; acc[i][3] += xs[i] * w0.w;
        acc[i][4] += xs[i] * w1.x; acc[i][5] += xs[i] * w1.y;
        acc[i][6] += xs[i] * w1.z; acc[i][7] += xs[i] * w1.w;
      }
    }
    __syncthreads();
  }
#pragma unroll
  for (int i = 0; i < 4; i++) {
    int n = nbase + n0 + i;
    if (n >= N_NODES) break;
#pragma unroll
    for (int j = 0; j < 8; j++) {
      int o = o0 + j;
      if (o < 64) {
        mu[(size_t)n * 64 + o] = acc[i][j] + bmu[o];
      } else {
        float s = acc[i][j] + bsig[o - 64];
        float e = (s > 0.f) ? s : (__expf(s) - 1.f);
        sig[(size_t)n * 64 + (o - 64)] = e + 1.f + 1e-14f;
      }
    }
  }
}

// ---------- K7: KL energies + mean reduce ----------
__global__ __launch_bounds__(256) void k_energy(const float* __restrict__ mu,
                                                const float* __restrict__ sig,
                                                const int* __restrict__ pos_e,
                                                const int* __restrict__ neg_e,
                                                float* __restrict__ out) {
  const int wid = (int)((blockIdx.x * blockDim.x + threadIdx.x) >> 6);
  const int lane = threadIdx.x & 63;
  if (wid >= 2 * NP) return;
  const bool ispos = wid < NP;
  const int* pr = ispos ? (pos_e + (size_t)wid * 2) : (neg_e + (size_t)(wid - NP) * 2);
  const int i = pr[0], j = pr[1];
  float mi = mu[(size_t)i * 64 + lane], mj = mu[(size_t)j * 64 + lane];
  float si = sig[(size_t)i * 64 + lane], sj = sig[(size_t)j * 64 + lane];
  float ratio = sj / si;
  float t1 = ratio;
  float t2 = logf(ratio + 1e-14f);
  float d = mi - mj;
  float t3 = d * d / si;
#pragma unroll
  for (int off = 32; off; off >>= 1) {
    t1 += __shfl_xor(t1, off);
    t2 += __shfl_xor(t2, off);
    t3 += __shfl_xor(t3, off);
  }
  if (lane == 0) {
    float eng = 0.5f * (t1 + t3 - 64.f - t2);
    float contrib = ispos ? (eng * eng) : __expf(-eng);
    atomicAdd(out, contrib * (1.f / NP));
  }
}

extern "C" void kernel_launch(void* const* d_in, const int* in_sizes, int n_in,
                              void* d_out, int out_size, void* d_ws, size_t ws_size,
                              hipStream_t stream) {
  const float* X = (const float*)d_in[0];
  const int* edge_idx = (const int*)d_in[1];
  const float* edge_vals = (const float*)d_in[2];
  const float* W = (const float*)d_in[3];
  const float* b = (const float*)d_in[4];
  const float* Wmu = (const float*)d_in[5];
  const float* bmu = (const float*)d_in[6];
  const float* Wsig = (const float*)d_in[7];
  const float* bsig = (const float*)d_in[8];
  const int* pos_e = (const int*)d_in[9];
  const int* neg_e = (const int*)d_in[10];
  float* out = (float*)d_out;

  char* ws = (char*)d_ws;
  const size_t o_xw    = 0;                       // V*N*H bf16 = 38,400,000
  const size_t o_cat   = 38400000;                // N*384 bf16 = 38,400,000
  const size_t o_mu    = 76800000;                // N*64 f32   = 12,800,000
  const size_t o_sig   = 89600000;                // N*64 f32   = 12,800,000
  const size_t o_cnt   = 102400000;               // V*N i32    =    600,000
  const size_t o_off   = 103000000;
  const size_t o_cur   = 103600000;
  const size_t o_spack = 104200000;               // V*E u32    = 19,200,000
  const size_t total   = 123400000;
  if (ws_size < total) return;

  unsigned* XWu = (unsigned*)(ws + o_xw);
  unsigned* cat = (unsigned*)(ws + o_cat);
  unsigned short* catus = (unsigned short*)(ws + o_cat);
  float* mu = (float*)(ws + o_mu);
  float* sig = (float*)(ws + o_sig);
  int* counts = (int*)(ws + o_cnt);
  int* offsets = (int*)(ws + o_off);
  int* cursor = (int*)(ws + o_cur);
  unsigned* spack = (unsigned*)(ws + o_spack);

  hipMemsetAsync(counts, 0, (size_t)NV * N_NODES * sizeof(int), stream);
  hipMemsetAsync(out, 0, sizeof(float), stream);

  // K1: XW
  dim3 g1((N_NODES + 63) / 64, NV);
  hipLaunchKernelGGL(k_gemm_xw, g1, dim3(256), 0, stream, X, W, XWu);
  // K2: count
  hipLaunchKernelGGL(k_count, dim3(1024, NV), dim3(256), 0, stream, edge_idx, counts);
  // K3: scan
  hipLaunchKernelGGL(k_scan, dim3(NV), dim3(1024), 0, stream, counts, offsets, cursor);
  // K4: scatter (packed 4B payload)
  hipLaunchKernelGGL(k_scatter, dim3(1024, NV), dim3(256), 0, stream, edge_idx, edge_vals,
                     cursor, spack);
  // K5: aggregate
  hipLaunchKernelGGL(k_agg, dim3((N_NODES + 3) / 4, NV), dim3(256), 0, stream,
                     counts, offsets, spack, XWu, b, cat);
  // K6: mu/sigma
  hipLaunchKernelGGL(k_musig, dim3((N_NODES + 63) / 64), dim3(256), 0, stream,
                     catus, Wmu, bmu, Wsig, bsig, mu, sig);
  // K7: energy
  hipLaunchKernelGGL(k_energy, dim3((2 * NP * 64 + 255) / 256), dim3(256), 0, stream,
                     mu, sig, pos_e, neg_e, out);
}

// Round 3
// 1561.923 us; speedup vs baseline: 1.2397x; 1.2397x over previous
//
#include <hip/hip_runtime.h>
#include <hip/hip_fp16.h>

#define N_NODES 50000
#define DIM 256
#define HID 128
#define LAT 64
#define NV 3
#define NE 1600000
#define NP 10000

// ---------- bf16 helpers (raw ushort/uint, RNE) ----------
__device__ __forceinline__ unsigned f2bf1(float f) {
  unsigned x = __float_as_uint(f);
  return (x + 0x7fffu + ((x >> 16) & 1u)) >> 16;
}
__device__ __forceinline__ unsigned pack2bf(float a, float b) {
  return (f2bf1(a) & 0xffffu) | (f2bf1(b) << 16);
}
__device__ __forceinline__ float bf2f(unsigned short u) {
  return __uint_as_float(((unsigned)u) << 16);
}

// ---------- K1: XW[v] = X @ W[v]  (f32 in, bf16 out) ----------
__global__ __launch_bounds__(256) void k_gemm_xw(const float* __restrict__ X,
                                                 const float* __restrict__ W,
                                                 unsigned* __restrict__ XWu) {
  const int v = blockIdx.y;
  const int nbase = blockIdx.x * 64;
  __shared__ float Xs[64][65];
  __shared__ float Ws[64][128];
  const int tid = threadIdx.x;
  const int hgrp = tid & 15, ngrp = tid >> 4;
  const int h0 = hgrp * 8, n0 = ngrp * 4;
  float acc[4][8];
#pragma unroll
  for (int i = 0; i < 4; i++)
#pragma unroll
    for (int j = 0; j < 8; j++) acc[i][j] = 0.f;
  const float* Wv = W + (size_t)v * DIM * HID;
  for (int kc = 0; kc < DIM; kc += 64) {
#pragma unroll
    for (int i = 0; i < 16; i++) {
      int idx = i * 256 + tid;
      int r = idx >> 6, c = idx & 63;
      int n = nbase + r;
      Xs[r][c] = (n < N_NODES) ? X[(size_t)n * DIM + kc + c] : 0.f;
    }
#pragma unroll
    for (int i = 0; i < 32; i++) {
      int idx = i * 256 + tid;
      int r = idx >> 7, c = idx & 127;
      Ws[r][c] = Wv[(size_t)(kc + r) * HID + c];
    }
    __syncthreads();
#pragma unroll 8
    for (int k = 0; k < 64; k++) {
      float4 w0 = *reinterpret_cast<const float4*>(&Ws[k][h0]);
      float4 w1 = *reinterpret_cast<const float4*>(&Ws[k][h0 + 4]);
      float xs[4];
#pragma unroll
      for (int i = 0; i < 4; i++) xs[i] = Xs[n0 + i][k];
#pragma unroll
      for (int i = 0; i < 4; i++) {
        acc[i][0] += xs[i] * w0.x; acc[i][1] += xs[i] * w0.y;
        acc[i][2] += xs[i] * w0.z; acc[i][3] += xs[i] * w0.w;
        acc[i][4] += xs[i] * w1.x; acc[i][5] += xs[i] * w1.y;
        acc[i][6] += xs[i] * w1.z; acc[i][7] += xs[i] * w1.w;
      }
    }
    __syncthreads();
  }
#pragma unroll
  for (int i = 0; i < 4; i++) {
    int n = nbase + n0 + i;
    if (n >= N_NODES) break;
    uint4 u;
    u.x = pack2bf(acc[i][0], acc[i][1]);
    u.y = pack2bf(acc[i][2], acc[i][3]);
    u.z = pack2bf(acc[i][4], acc[i][5]);
    u.w = pack2bf(acc[i][6], acc[i][7]);
    *reinterpret_cast<uint4*>(XWu + (((size_t)v * N_NODES + n) * HID + h0) / 2) = u;
  }
}

// ---------- K2: histogram of dst per view ----------
__global__ void k_count(const int* __restrict__ edge_idx, int* __restrict__ counts) {
  const int v = blockIdx.y;
  const int stride = gridDim.x * blockDim.x;
  for (int e = blockIdx.x * blockDim.x + threadIdx.x; e < NE; e += stride) {
    int2 sd = reinterpret_cast<const int2*>(edge_idx)[(size_t)v * NE + e];
    atomicAdd(&counts[v * N_NODES + sd.y], 1);
  }
}

// ---------- K3: exclusive scan per view (shfl-based, 2 barriers/chunk) ----------
__global__ __launch_bounds__(1024) void k_scan(const int* __restrict__ counts,
                                               int* __restrict__ offsets,
                                               int* __restrict__ cursor) {
  const int v = blockIdx.x;
  __shared__ int wsum[16];
  __shared__ int carry_s;
  const int tid = threadIdx.x;
  const int lane = tid & 63, wv = tid >> 6;
  if (tid == 0) carry_s = 0;
  __syncthreads();
  for (int base = 0; base < N_NODES; base += 1024) {
    int i = base + tid;
    int val = (i < N_NODES) ? counts[v * N_NODES + i] : 0;
    int x = val;  // inclusive wave scan
#pragma unroll
    for (int off = 1; off < 64; off <<= 1) {
      int t = __shfl_up(x, off);
      if (lane >= off) x += t;
    }
    if (lane == 63) wsum[wv] = x;
    __syncthreads();
    int wpre = 0;
#pragma unroll
    for (int w = 0; w < 15; w++) wpre += (w < wv) ? wsum[w] : 0;
    int excl = carry_s + wpre + x - val;
    if (i < N_NODES) {
      offsets[v * N_NODES + i] = excl;
      cursor[v * N_NODES + i] = excl;
    }
    __syncthreads();
    if (tid == 1023) carry_s += wpre + x;
    __syncthreads();
  }
}

// ---------- K4: rank-scatter edges; payload packed to 4B (src:16 | f16 val:16) ----------
__global__ void k_scatter(const int* __restrict__ edge_idx,
                          const float* __restrict__ edge_vals,
                          int* __restrict__ cursor,
                          unsigned* __restrict__ spack) {
  const int v = blockIdx.y;
  const int stride = gridDim.x * blockDim.x;
  for (int e = blockIdx.x * blockDim.x + threadIdx.x; e < NE; e += stride) {
    size_t eb = (size_t)v * NE + e;
    int2 sd = reinterpret_cast<const int2*>(edge_idx)[eb];  // (src, dst)
    float val = edge_vals[eb];
    int pos = atomicAdd(&cursor[v * N_NODES + sd.y], 1);
    unsigned h = (unsigned)__half_as_ushort(__float2half(val));
    spack[(size_t)v * NE + pos] = (((unsigned)sd.x) << 16) | h;
  }
}

// ---------- K5: CSR aggregate + bias + relu -> concat (bf16) ----------
// 16-deep batched gather: padding lanes carry p=0 (src=0, val=+0.0h) so the
// inner loop has NO predication and all 16 loads are in flight together.
__global__ __launch_bounds__(256) void k_agg(const int* __restrict__ counts,
                                             const int* __restrict__ offsets,
                                             const unsigned* __restrict__ spack,
                                             const unsigned* __restrict__ XWu,
                                             const float* __restrict__ b,
                                             unsigned* __restrict__ cat) {
  const int v = blockIdx.y;
  const int wave = threadIdx.x >> 6;
  const int lane = threadIdx.x & 63;
  const int n = blockIdx.x * 4 + wave;
  if (n >= N_NODES) return;
  const int cnt = counts[v * N_NODES + n];
  const int base = offsets[v * N_NODES + n];
  const unsigned* xw = XWu + (size_t)v * N_NODES * 64;  // 64 uints (=128 bf16) per row
  const unsigned* pp = spack + (size_t)v * NE + base;
  float a0 = 0.f, a1 = 0.f;
  for (int c0 = 0; c0 < cnt; c0 += 64) {
    const int m = min(64, cnt - c0);
    unsigned p = (lane < m) ? pp[c0 + lane] : 0u;  // pad: src=0, val=0
    for (int jb = 0; jb < m; jb += 16) {
      unsigned u[16];
      float vals[16];
#pragma unroll
      for (int k = 0; k < 16; k++) {
        unsigned pj = (unsigned)__shfl((int)p, jb + k);
        vals[k] = __half2float(__ushort_as_half((unsigned short)(pj & 0xffffu)));
        u[k] = xw[(size_t)(pj >> 16) * 64 + lane];
      }
#pragma unroll
      for (int k = 0; k < 16; k++) {
        a0 += vals[k] * __uint_as_float(u[k] << 16);
        a1 += vals[k] * __uint_as_float(u[k] & 0xffff0000u);
      }
    }
  }
  float h0 = a0 + b[v * HID + 2 * lane];
  float h1 = a1 + b[v * HID + 2 * lane + 1];
  h0 = h0 > 0.f ? h0 : 0.f;
  h1 = h1 > 0.f ? h1 : 0.f;
  cat[(size_t)n * 192 + v * 64 + lane] = pack2bf(h0, h1);
}

// ---------- K6: mu/sigma = concat @ [Wmu|Wsig] + bias, elu ----------
__global__ __launch_bounds__(256) void k_musig(const unsigned short* __restrict__ catus,
                                               const float* __restrict__ Wmu,
                                               const float* __restrict__ bmu,
                                               const float* __restrict__ Wsig,
                                               const float* __restrict__ bsig,
                                               float* __restrict__ mu,
                                               float* __restrict__ sig) {
  const int nbase = blockIdx.x * 64;
  __shared__ float Cs[64][65];
  __shared__ float Ws[64][128];
  const int tid = threadIdx.x;
  const int ogrp = tid & 15, ngrp = tid >> 4;
  const int o0 = ogrp * 8, n0 = ngrp * 4;
  float acc[4][8];
#pragma unroll
  for (int i = 0; i < 4; i++)
#pragma unroll
    for (int j = 0; j < 8; j++) acc[i][j] = 0.f;
  for (int kc = 0; kc < 384; kc += 64) {
#pragma unroll
    for (int i = 0; i < 16; i++) {
      int idx = i * 256 + tid;
      int r = idx >> 6, c = idx & 63;
      int n = nbase + r;
      Cs[r][c] = (n < N_NODES) ? bf2f(catus[(size_t)n * 384 + kc + c]) : 0.f;
    }
#pragma unroll
    for (int i = 0; i < 32; i++) {
      int idx = i * 256 + tid;
      int r = idx >> 7, c = idx & 127;
      int k = kc + r;
      Ws[r][c] = (c < 64) ? Wmu[(size_t)k * 64 + c] : Wsig[(size_t)k * 64 + (c - 64)];
    }
    __syncthreads();
#pragma unroll 8
    for (int k = 0; k < 64; k++) {
      float4 w0 = *reinterpret_cast<const float4*>(&Ws[k][o0]);
      float4 w1 = *reinterpret_cast<const float4*>(&Ws[k][o0 + 4]);
      float xs[4];
#pragma unroll
      for (int i = 0; i < 4; i++) xs[i] = Cs[n0 + i][k];
#pragma unroll
      for (int i = 0; i < 4; i++) {
        acc[i][0] += xs[i] * w0.x; acc[i][1] += xs[i] * w0.y;
        acc[i][2] += xs[i] * w0.z; acc[i][3] += xs[i] * w0.w;
        acc[i][4] += xs[i] * w1.x; acc[i][5] += xs[i] * w1.y;
        acc[i][6] += xs[i] * w1.z; acc[i][7] += xs[i] * w1.w;
      }
    }
    __syncthreads();
  }
#pragma unroll
  for (int i = 0; i < 4; i++) {
    int n = nbase + n0 + i;
    if (n >= N_NODES) break;
#pragma unroll
    for (int j = 0; j < 8; j++) {
      int o = o0 + j;
      if (o < 64) {
        mu[(size_t)n * 64 + o] = acc[i][j] + bmu[o];
      } else {
        float s = acc[i][j] + bsig[o - 64];
        float e = (s > 0.f) ? s : (__expf(s) - 1.f);
        sig[(size_t)n * 64 + (o - 64)] = e + 1.f + 1e-14f;
      }
    }
  }
}

// ---------- K7: KL energies + mean reduce ----------
__global__ __launch_bounds__(256) void k_energy(const float* __restrict__ mu,
                                                const float* __restrict__ sig,
                                                const int* __restrict__ pos_e,
                                                const int* __restrict__ neg_e,
                                                float* __restrict__ out) {
  const int wid = (int)((blockIdx.x * blockDim.x + threadIdx.x) >> 6);
  const int lane = threadIdx.x & 63;
  if (wid >= 2 * NP) return;
  const bool ispos = wid < NP;
  const int* pr = ispos ? (pos_e + (size_t)wid * 2) : (neg_e + (size_t)(wid - NP) * 2);
  const int i = pr[0], j = pr[1];
  float mi = mu[(size_t)i * 64 + lane], mj = mu[(size_t)j * 64 + lane];
  float si = sig[(size_t)i * 64 + lane], sj = sig[(size_t)j * 64 + lane];
  float ratio = sj / si;
  float t1 = ratio;
  float t2 = logf(ratio + 1e-14f);
  float d = mi - mj;
  float t3 = d * d / si;
#pragma unroll
  for (int off = 32; off; off >>= 1) {
    t1 += __shfl_xor(t1, off);
    t2 += __shfl_xor(t2, off);
    t3 += __shfl_xor(t3, off);
  }
  if (lane == 0) {
    float eng = 0.5f * (t1 + t3 - 64.f - t2);
    float contrib = ispos ? (eng * eng) : __expf(-eng);
    atomicAdd(out, contrib * (1.f / NP));
  }
}

extern "C" void kernel_launch(void* const* d_in, const int* in_sizes, int n_in,
                              void* d_out, int out_size, void* d_ws, size_t ws_size,
                              hipStream_t stream) {
  const float* X = (const float*)d_in[0];
  const int* edge_idx = (const int*)d_in[1];
  const float* edge_vals = (const float*)d_in[2];
  const float* W = (const float*)d_in[3];
  const float* b = (const float*)d_in[4];
  const float* Wmu = (const float*)d_in[5];
  const float* bmu = (const float*)d_in[6];
  const float* Wsig = (const float*)d_in[7];
  const float* bsig = (const float*)d_in[8];
  const int* pos_e = (const int*)d_in[9];
  const int* neg_e = (const int*)d_in[10];
  float* out = (float*)d_out;

  char* ws = (char*)d_ws;
  const size_t o_xw    = 0;                       // V*N*H bf16 = 38,400,000
  const size_t o_cat   = 38400000;                // N*384 bf16 = 38,400,000
  const size_t o_mu    = 76800000;                // N*64 f32   = 12,800,000
  const size_t o_sig   = 89600000;                // N*64 f32   = 12,800,000
  const size_t o_cnt   = 102400000;               // V*N i32    =    600,000
  const size_t o_off   = 103000000;
  const size_t o_cur   = 103600000;
  const size_t o_spack = 104200000;               // V*E u32    = 19,200,000
  const size_t total   = 123400000;
  if (ws_size < total) return;

  unsigned* XWu = (unsigned*)(ws + o_xw);
  unsigned* cat = (unsigned*)(ws + o_cat);
  unsigned short* catus = (unsigned short*)(ws + o_cat);
  float* mu = (float*)(ws + o_mu);
  float* sig = (float*)(ws + o_sig);
  int* counts = (int*)(ws + o_cnt);
  int* offsets = (int*)(ws + o_off);
  int* cursor = (int*)(ws + o_cur);
  unsigned* spack = (unsigned*)(ws + o_spack);

  hipMemsetAsync(counts, 0, (size_t)NV * N_NODES * sizeof(int), stream);
  hipMemsetAsync(out, 0, sizeof(float), stream);

  // K1: XW
  dim3 g1((N_NODES + 63) / 64, NV);
  hipLaunchKernelGGL(k_gemm_xw, g1, dim3(256), 0, stream, X, W, XWu);
  // K2: count
  hipLaunchKernelGGL(k_count, dim3(1024, NV), dim3(256), 0, stream, edge_idx, counts);
  // K3: scan
  hipLaunchKernelGGL(k_scan, dim3(NV), dim3(1024), 0, stream, counts, offsets, cursor);
  // K4: scatter (packed 4B payload)
  hipLaunchKernelGGL(k_scatter, dim3(1024, NV), dim3(256), 0, stream, edge_idx, edge_vals,
                     cursor, spack);
  // K5: aggregate (16-deep MLP gather)
  hipLaunchKernelGGL(k_agg, dim3((N_NODES + 3) / 4, NV), dim3(256), 0, stream,
                     counts, offsets, spack, XWu, b, cat);
  // K6: mu/sigma
  hipLaunchKernelGGL(k_musig, dim3((N_NODES + 63) / 64), dim3(256), 0, stream,
                     catus, Wmu, bmu, Wsig, bsig, mu, sig);
  // K7: energy
  hipLaunchKernelGGL(k_energy, dim3((2 * NP * 64 + 255) / 256), dim3(256), 0, stream,
                     mu, sig, pos_e, neg_e, out);
}